// Round 1
// baseline (9984.004 us; speedup 1.0000x reference)
//
#include <hip/hip_runtime.h>
#include <math.h>

#define N_NODES 16000
#define N_EDGES 128000
#define IN_FEAT 1024
#define OUT_FEAT 1024
#define N_RELS 7
#define NB_GOS 4096

#define BM 64
#define BN 64
#define BK 16
#define CAP (N_EDGES + N_RELS * BM)   // 128448, divisible by 64
#define NTILE_E (CAP / BM)            // 2007

// ---------------- bucket setup ----------------

__global__ void init_buckets(int* cnt, int* cursor, int* bucket) {
    int i = blockIdx.x * 256 + threadIdx.x;
    if (i < 8) { cnt[i] = 0; cursor[i] = 0; }
    if (i < CAP) bucket[i] = -1;
}

__global__ void count_etypes(const int* __restrict__ et, int* cnt) {
    int e = blockIdx.x * 256 + threadIdx.x;
    if (e < N_EDGES) atomicAdd(&cnt[et[e]], 1);
}

__global__ void calc_offsets(const int* __restrict__ cnt, int* offs) {
    if (blockIdx.x == 0 && threadIdx.x == 0) {
        int acc = 0;
        offs[0] = 0;
        for (int r = 0; r < N_RELS; r++) {
            acc += ((cnt[r] + BM - 1) / BM) * BM;
            offs[r + 1] = acc;
        }
    }
}

__global__ void scatter_edges(const int* __restrict__ et, const int* __restrict__ offs,
                              int* cursor, int* bucket) {
    int e = blockIdx.x * 256 + threadIdx.x;
    if (e < N_EDGES) {
        int r = et[e];
        int p = atomicAdd(&cursor[r], 1);
        bucket[offs[r] + p] = e;
    }
}

// ---------------- GEMM 1: h = feat @ W_loop + bias ----------------

__global__ __launch_bounds__(256) void gemm_loop(const float* __restrict__ A,
                                                 const float* __restrict__ B,
                                                 const float* __restrict__ bias,
                                                 float* __restrict__ H) {
    __shared__ float As[BK][BM + 1];
    __shared__ float Bs[BK][BN + 1];
    int tid = threadIdx.x;
    int m0 = blockIdx.y * BM, n0 = blockIdx.x * BN;
    float acc[4][4] = {};
    int la_k = tid % BK;       // 0..15
    int la_m = tid / BK;       // 0..15 (rows la_m + 16*i)
    int lb_n = tid % BN;       // 0..63
    int lb_k = tid / BN;       // 0..3 (ks lb_k + 4*i)
    int tx = tid % 16, ty = tid / 16;

    for (int k0 = 0; k0 < IN_FEAT; k0 += BK) {
        #pragma unroll
        for (int i = 0; i < 4; i++)
            As[la_k][la_m + 16 * i] = A[(size_t)(m0 + la_m + 16 * i) * IN_FEAT + k0 + la_k];
        #pragma unroll
        for (int i = 0; i < 4; i++)
            Bs[lb_k + 4 * i][lb_n] = B[(size_t)(k0 + lb_k + 4 * i) * OUT_FEAT + n0 + lb_n];
        __syncthreads();
        #pragma unroll
        for (int kk = 0; kk < BK; kk++) {
            float a[4], b[4];
            #pragma unroll
            for (int i = 0; i < 4; i++) a[i] = As[kk][ty * 4 + i];
            #pragma unroll
            for (int j = 0; j < 4; j++) b[j] = Bs[kk][tx * 4 + j];
            #pragma unroll
            for (int i = 0; i < 4; i++)
                #pragma unroll
                for (int j = 0; j < 4; j++) acc[i][j] += a[i] * b[j];
        }
        __syncthreads();
    }
    #pragma unroll
    for (int i = 0; i < 4; i++)
        #pragma unroll
        for (int j = 0; j < 4; j++)
            H[(size_t)(m0 + ty * 4 + i) * OUT_FEAT + n0 + tx * 4 + j] =
                acc[i][j] + bias[n0 + tx * 4 + j];
}

// ---------------- GEMM 2: h[dst] += feat[src] @ W_rel[etype] ----------------

__global__ __launch_bounds__(256) void gemm_edges(const float* __restrict__ feat,
                                                  const float* __restrict__ Wrel,
                                                  const int* __restrict__ src,
                                                  const int* __restrict__ dst,
                                                  const int* __restrict__ bucket,
                                                  const int* __restrict__ offs,
                                                  float* H) {
    __shared__ float As[BK][BM + 1];
    __shared__ float Bs[BK][BN + 1];
    __shared__ int s_src[BM], s_dst[BM];
    __shared__ int s_rel;
    int tid = threadIdx.x;
    int t0 = blockIdx.y * BM;
    int n0 = blockIdx.x * BN;

    if (tid < BM) {
        int e = bucket[t0 + tid];
        s_src[tid] = (e >= 0) ? src[e] : -1;
        s_dst[tid] = (e >= 0) ? dst[e] : -1;
    }
    if (tid == 0) {
        int r = -1;
        for (int q = 0; q < N_RELS; q++)
            if (t0 >= offs[q] && t0 < offs[q + 1]) r = q;
        s_rel = r;
    }
    __syncthreads();
    int rel = s_rel;
    if (rel < 0) return;   // tile entirely past the padded buckets

    const float* B = Wrel + (size_t)rel * IN_FEAT * OUT_FEAT;

    float acc[4][4] = {};
    int la_k = tid % BK;
    int la_m = tid / BK;
    int lb_n = tid % BN;
    int lb_k = tid / BN;
    int tx = tid % 16, ty = tid / 16;

    for (int k0 = 0; k0 < IN_FEAT; k0 += BK) {
        #pragma unroll
        for (int i = 0; i < 4; i++) {
            int srow = s_src[la_m + 16 * i];
            As[la_k][la_m + 16 * i] =
                (srow >= 0) ? feat[(size_t)srow * IN_FEAT + k0 + la_k] : 0.0f;
        }
        #pragma unroll
        for (int i = 0; i < 4; i++)
            Bs[lb_k + 4 * i][lb_n] = B[(size_t)(k0 + lb_k + 4 * i) * OUT_FEAT + n0 + lb_n];
        __syncthreads();
        #pragma unroll
        for (int kk = 0; kk < BK; kk++) {
            float a[4], b[4];
            #pragma unroll
            for (int i = 0; i < 4; i++) a[i] = As[kk][ty * 4 + i];
            #pragma unroll
            for (int j = 0; j < 4; j++) b[j] = Bs[kk][tx * 4 + j];
            #pragma unroll
            for (int i = 0; i < 4; i++)
                #pragma unroll
                for (int j = 0; j < 4; j++) acc[i][j] += a[i] * b[j];
        }
        __syncthreads();
    }
    #pragma unroll
    for (int i = 0; i < 4; i++) {
        int d = s_dst[ty * 4 + i];
        if (d >= 0) {
            #pragma unroll
            for (int j = 0; j < 4; j++)
                atomicAdd(&H[(size_t)d * OUT_FEAT + n0 + tx * 4 + j], acc[i][j]);
        }
    }
}

// ---------------- GEMM 3: out = sigmoid(h @ go_embed^T + |rad|) ----------------

__global__ __launch_bounds__(256) void gemm_score(const float* __restrict__ H,
                                                  const float* __restrict__ G,
                                                  const float* __restrict__ rad,
                                                  float* __restrict__ out) {
    __shared__ float As[BK][BM + 1];
    __shared__ float Bs[BK][BN + 1];
    int tid = threadIdx.x;
    int m0 = blockIdx.y * BM, n0 = blockIdx.x * BN;
    float acc[4][4] = {};
    int la_k = tid % BK;
    int la_m = tid / BK;
    int lg_k = tid % BK;       // 0..15 (k)
    int lg_n = tid / BK;       // 0..15 (n = lg_n + 16*i)
    int tx = tid % 16, ty = tid / 16;

    for (int k0 = 0; k0 < OUT_FEAT; k0 += BK) {
        #pragma unroll
        for (int i = 0; i < 4; i++)
            As[la_k][la_m + 16 * i] = H[(size_t)(m0 + la_m + 16 * i) * OUT_FEAT + k0 + la_k];
        #pragma unroll
        for (int i = 0; i < 4; i++)
            Bs[lg_k][lg_n + 16 * i] = G[(size_t)(n0 + lg_n + 16 * i) * OUT_FEAT + k0 + lg_k];
        __syncthreads();
        #pragma unroll
        for (int kk = 0; kk < BK; kk++) {
            float a[4], b[4];
            #pragma unroll
            for (int i = 0; i < 4; i++) a[i] = As[kk][ty * 4 + i];
            #pragma unroll
            for (int j = 0; j < 4; j++) b[j] = Bs[kk][tx * 4 + j];
            #pragma unroll
            for (int i = 0; i < 4; i++)
                #pragma unroll
                for (int j = 0; j < 4; j++) acc[i][j] += a[i] * b[j];
        }
        __syncthreads();
    }
    #pragma unroll
    for (int i = 0; i < 4; i++)
        #pragma unroll
        for (int j = 0; j < 4; j++) {
            float x = acc[i][j] + fabsf(rad[n0 + tx * 4 + j]);
            out[(size_t)(m0 + ty * 4 + i) * NB_GOS + n0 + tx * 4 + j] =
                1.0f / (1.0f + expf(-x));
        }
}

// ---------------- launch ----------------

extern "C" void kernel_launch(void* const* d_in, const int* in_sizes, int n_in,
                              void* d_out, int out_size, void* d_ws, size_t ws_size,
                              hipStream_t stream) {
    const float* feat   = (const float*)d_in[0];
    const int*   src    = (const int*)d_in[1];
    const int*   dst    = (const int*)d_in[2];
    const int*   etypes = (const int*)d_in[3];
    const float* W_rel  = (const float*)d_in[4];
    const float* W_loop = (const float*)d_in[5];
    const float* bias   = (const float*)d_in[6];
    const float* go_emb = (const float*)d_in[7];
    const float* go_rad = (const float*)d_in[8];
    float* out = (float*)d_out;

    // workspace layout
    float* h    = (float*)d_ws;                                  // 16000*1024 f32
    char*  p    = (char*)d_ws + (size_t)N_NODES * OUT_FEAT * 4;
    int* cnt    = (int*)p;          // 8
    int* cursor = cnt + 8;          // 8
    int* offs   = cursor + 8;       // 16
    int* bucket = offs + 16;        // CAP

    init_buckets<<<(CAP + 255) / 256, 256, 0, stream>>>(cnt, cursor, bucket);
    count_etypes<<<(N_EDGES + 255) / 256, 256, 0, stream>>>(etypes, cnt);
    calc_offsets<<<1, 64, 0, stream>>>(cnt, offs);
    scatter_edges<<<(N_EDGES + 255) / 256, 256, 0, stream>>>(etypes, offs, cursor, bucket);

    // h = feat @ W_loop + bias
    dim3 g1(OUT_FEAT / BN, N_NODES / BM);
    gemm_loop<<<g1, 256, 0, stream>>>(feat, W_loop, bias, h);

    // h[dst] += feat[src] @ W_rel[etype]
    dim3 g2(OUT_FEAT / BN, NTILE_E);
    gemm_edges<<<g2, 256, 0, stream>>>(feat, W_rel, src, dst, bucket, offs, h);

    // out = sigmoid(h @ go_embed^T + |rad|)
    dim3 g3(NB_GOS / BN, N_NODES / BM);
    gemm_score<<<g3, 256, 0, stream>>>(h, go_emb, go_rad, out);
}

// Round 2
// 2116.425 us; speedup vs baseline: 4.7174x; 4.7174x over previous
//
#include <hip/hip_runtime.h>
#include <math.h>

#define N_NODES 16000
#define N_EDGES 128000
#define KDIM 1024
#define N_RELS 7
#define NB_GOS 4096

#define BM 128
#define BN 128
#define BK 32
#define CAP2 (N_EDGES + N_RELS * BM)   // 128896 = 1007 * 128
#define NTILE_E (CAP2 / BM)            // 1007

typedef __attribute__((ext_vector_type(8))) short bf16x8;
typedef __attribute__((ext_vector_type(8))) unsigned short u16x8;
typedef __attribute__((ext_vector_type(4))) float f32x4;

__device__ __forceinline__ unsigned short f2bf(float f) {
    union { float f; unsigned int u; } v; v.f = f;
    unsigned int u = v.u + 0x7FFFu + ((v.u >> 16) & 1u);   // RNE
    return (unsigned short)(u >> 16);
}

__device__ __forceinline__ void gload16(const void* g, void* lds) {
    __builtin_amdgcn_global_load_lds(
        (const __attribute__((address_space(1))) unsigned int*)g,
        (__attribute__((address_space(3))) unsigned int*)lds, 16, 0, 0);
}

// ---------------- prep: fp32 -> bf16 (8 elements/thread) ----------------

__global__ __launch_bounds__(256) void conv_bf16(const float* __restrict__ in,
                                                 unsigned short* __restrict__ out, int n8) {
    int i = blockIdx.x * 256 + threadIdx.x;
    if (i >= n8) return;
    const float4* in4 = (const float4*)in;
    float4 x = in4[2 * i], y = in4[2 * i + 1];
    u16x8 o;
    o[0] = f2bf(x.x); o[1] = f2bf(x.y); o[2] = f2bf(x.z); o[3] = f2bf(x.w);
    o[4] = f2bf(y.x); o[5] = f2bf(y.y); o[6] = f2bf(y.z); o[7] = f2bf(y.w);
    *(u16x8*)&out[(size_t)i * 8] = o;
}

// transpose W ([K][N] fp32) -> [N][K] bf16, 8 matrices (7 W_rel + W_loop)
__global__ __launch_bounds__(256) void transpose_w(const float* __restrict__ Wrel,
                                                   const float* __restrict__ Wloop,
                                                   unsigned short* __restrict__ WrelT,
                                                   unsigned short* __restrict__ WloopT) {
    __shared__ float t[32][33];
    int z = blockIdx.z;
    const float* src = (z < N_RELS) ? Wrel + (size_t)z * KDIM * KDIM : Wloop;
    unsigned short* dst = (z < N_RELS) ? WrelT + (size_t)z * KDIM * KDIM : WloopT;
    int tx = threadIdx.x, ty = threadIdx.y;      // 32 x 8
    int x = blockIdx.x * 32 + tx;                // n
    int y0 = blockIdx.y * 32;                    // k base
    #pragma unroll
    for (int j = 0; j < 4; j++)
        t[ty + 8 * j][tx] = src[(size_t)(y0 + ty + 8 * j) * KDIM + x];
    __syncthreads();
    #pragma unroll
    for (int j = 0; j < 4; j++) {
        int n = blockIdx.x * 32 + ty + 8 * j;
        dst[(size_t)n * KDIM + y0 + tx] = f2bf(t[tx][ty + 8 * j]);
    }
}

// ---------------- bucket setup ----------------

__global__ void init_buckets(int* cnt, int* cursor, int* bucket) {
    int i = blockIdx.x * 256 + threadIdx.x;
    if (i < 8) { cnt[i] = 0; cursor[i] = 0; }
    if (i < CAP2) bucket[i] = -1;
}

__global__ void count_etypes(const int* __restrict__ et, int* cnt) {
    int e = blockIdx.x * 256 + threadIdx.x;
    if (e < N_EDGES) atomicAdd(&cnt[et[e]], 1);
}

__global__ void calc_offsets(const int* __restrict__ cnt, int* offs) {
    if (blockIdx.x == 0 && threadIdx.x == 0) {
        int acc = 0;
        offs[0] = 0;
        for (int r = 0; r < N_RELS; r++) {
            acc += ((cnt[r] + BM - 1) / BM) * BM;
            offs[r + 1] = acc;
        }
    }
}

__global__ void scatter_edges(const int* __restrict__ et, const int* __restrict__ offs,
                              int* cursor, int* bucket) {
    int e = blockIdx.x * 256 + threadIdx.x;
    if (e < N_EDGES) {
        int r = et[e];
        int p = atomicAdd(&cursor[r], 1);
        bucket[offs[r] + p] = e;
    }
}

// ---------------- MFMA GEMM: 128x128 tile, BK=32, 4 waves (2x2) ----------------
// MODE 0: H[m] = feat @ W_loop^T(staged) + bias          (plain store, stride 1024)
// MODE 1: H[dst] += feat[src] @ W_rel[rel]               (atomicAdd, stride 1024)
// MODE 2: out[m] = sigmoid(h @ go^T + |rad|)             (store, stride 4096)

template<int MODE>
__global__ __launch_bounds__(256) void mfma_gemm(
    const unsigned short* __restrict__ A,    // [*,1024] bf16
    const unsigned short* __restrict__ BT,   // [*,1024] bf16, rows = output cols
    const float* __restrict__ br,            // bias (MODE0) / rad (MODE2)
    float* __restrict__ out,
    const int* __restrict__ src,
    const int* __restrict__ dst,
    const int* __restrict__ bucket,
    const int* __restrict__ offs)
{
    __shared__ unsigned short As[BM * BK];
    __shared__ unsigned short Bs[BN * BK];
    __shared__ int s_src[BM];
    __shared__ int s_dst[BM];

    const int tid = threadIdx.x;
    const int l = tid & 63;
    const int w = tid >> 6;
    const int wr = w >> 1, wc = w & 1;
    const int n0 = blockIdx.x * BN;
    const int m0 = blockIdx.y * BM;

    const unsigned short* Bb = BT;
    if (MODE == 1) {
        int rel = -1;
        #pragma unroll
        for (int q = 0; q < N_RELS; q++)
            if (m0 >= offs[q] && m0 < offs[q + 1]) rel = q;
        if (rel < 0) return;                       // uniform: tile past padded buckets
        Bb = BT + (size_t)rel * KDIM * KDIM;
        if (tid < BM) {
            int e = bucket[m0 + tid];
            s_src[tid] = (e >= 0) ? src[e] : -1;
            s_dst[tid] = (e >= 0) ? dst[e] : -1;
        }
        __syncthreads();
    }

    f32x4 acc[4][4] = {};

    // staging: 512 16B slots per operand; thread t owns slots t and t+256.
    const int s0 = tid, s1 = tid + 256;
    const int r0 = s0 >> 2, kc0 = (s0 & 3) * 8;
    const int r1 = s1 >> 2, kc1 = (s1 & 3) * 8;
    unsigned short* ldsA0 = As + (w * 64) * 8;           // wave-uniform bases
    unsigned short* ldsA1 = As + (w * 64 + 256) * 8;
    unsigned short* ldsB0 = Bs + (w * 64) * 8;
    unsigned short* ldsB1 = Bs + (w * 64 + 256) * 8;

    size_t arow0, arow1;
    if (MODE == 1) {
        int sr0 = s_src[r0]; arow0 = (sr0 < 0) ? 0 : (size_t)sr0;  // pad rows: clamp, dropped at epilogue
        int sr1 = s_src[r1]; arow1 = (sr1 < 0) ? 0 : (size_t)sr1;
    } else {
        arow0 = (size_t)(m0 + r0);
        arow1 = (size_t)(m0 + r1);
    }
    const size_t brow0 = (size_t)(n0 + r0), brow1 = (size_t)(n0 + r1);

    const int fa = (wr * 64 + (l & 15)) * BK + (l >> 4) * 8;
    const int fb = (wc * 64 + (l & 15)) * BK + (l >> 4) * 8;

    for (int k0 = 0; k0 < KDIM; k0 += BK) {
        gload16(A + arow0 * KDIM + k0 + kc0, ldsA0);
        gload16(A + arow1 * KDIM + k0 + kc1, ldsA1);
        gload16(Bb + brow0 * KDIM + k0 + kc0, ldsB0);
        gload16(Bb + brow1 * KDIM + k0 + kc1, ldsB1);
        __syncthreads();

        bf16x8 a[4], b[4];
        #pragma unroll
        for (int mi = 0; mi < 4; mi++)
            a[mi] = *(const bf16x8*)&As[fa + mi * 16 * BK];
        #pragma unroll
        for (int nj = 0; nj < 4; nj++)
            b[nj] = *(const bf16x8*)&Bs[fb + nj * 16 * BK];
        #pragma unroll
        for (int mi = 0; mi < 4; mi++)
            #pragma unroll
            for (int nj = 0; nj < 4; nj++)
                acc[mi][nj] = __builtin_amdgcn_mfma_f32_16x16x32_bf16(a[mi], b[nj], acc[mi][nj], 0, 0, 0);
        __syncthreads();
    }

    // epilogue — verified C/D layout: col = lane&15, row = (lane>>4)*4 + reg
    const int cl = l & 15, rh = (l >> 4) * 4;
    #pragma unroll
    for (int mi = 0; mi < 4; mi++) {
        #pragma unroll
        for (int r4 = 0; r4 < 4; r4++) {
            const int row = wr * 64 + mi * 16 + rh + r4;
            if (MODE == 1) {
                const int d = s_dst[row];
                if (d >= 0) {
                    #pragma unroll
                    for (int nj = 0; nj < 4; nj++) {
                        const int col = n0 + wc * 64 + nj * 16 + cl;
                        atomicAdd(&out[(size_t)d * KDIM + col], acc[mi][nj][r4]);
                    }
                }
            } else if (MODE == 0) {
                #pragma unroll
                for (int nj = 0; nj < 4; nj++) {
                    const int col = n0 + wc * 64 + nj * 16 + cl;
                    out[(size_t)(m0 + row) * KDIM + col] = acc[mi][nj][r4] + br[col];
                }
            } else {
                #pragma unroll
                for (int nj = 0; nj < 4; nj++) {
                    const int col = n0 + wc * 64 + nj * 16 + cl;
                    float x = acc[mi][nj][r4] + fabsf(br[col]);
                    out[(size_t)(m0 + row) * (size_t)NB_GOS + col] = 1.0f / (1.0f + expf(-x));
                }
            }
        }
    }
}

// ---------------- launch ----------------

extern "C" void kernel_launch(void* const* d_in, const int* in_sizes, int n_in,
                              void* d_out, int out_size, void* d_ws, size_t ws_size,
                              hipStream_t stream) {
    const float* feat   = (const float*)d_in[0];
    const int*   src    = (const int*)d_in[1];
    const int*   dst    = (const int*)d_in[2];
    const int*   etypes = (const int*)d_in[3];
    const float* W_rel  = (const float*)d_in[4];
    const float* W_loop = (const float*)d_in[5];
    const float* bias   = (const float*)d_in[6];
    const float* go_emb = (const float*)d_in[7];
    const float* go_rad = (const float*)d_in[8];
    float* out = (float*)d_out;

    // workspace layout (all offsets 256B-aligned); total ~124 MB
    char* p = (char*)d_ws;
    float* h            = (float*)p;            p += (size_t)N_NODES * KDIM * 4;     // 65,536,000
    unsigned short* fb  = (unsigned short*)p;   p += (size_t)N_NODES * KDIM * 2;     // 32,768,000 (reused as h_bf16)
    unsigned short* wrT = (unsigned short*)p;   p += (size_t)N_RELS * KDIM * KDIM * 2; // 14,680,064
    unsigned short* wlT = (unsigned short*)p;   p += (size_t)KDIM * KDIM * 2;        // 2,097,152
    unsigned short* gob = (unsigned short*)p;   p += (size_t)NB_GOS * KDIM * 2;      // 8,388,608
    int* cnt    = (int*)p;
    int* cursor = cnt + 8;
    int* offs   = cursor + 8;
    int* bucket = offs + 16;

    // prep: conversions + transposes + buckets
    conv_bf16<<<(N_NODES * KDIM / 8 + 255) / 256, 256, 0, stream>>>(feat, fb, N_NODES * KDIM / 8);
    conv_bf16<<<(NB_GOS * KDIM / 8 + 255) / 256, 256, 0, stream>>>(go_emb, gob, NB_GOS * KDIM / 8);
    {
        dim3 g(KDIM / 32, KDIM / 32, N_RELS + 1), b(32, 8);
        transpose_w<<<g, b, 0, stream>>>(W_rel, W_loop, wrT, wlT);
    }
    init_buckets<<<(CAP2 + 255) / 256, 256, 0, stream>>>(cnt, cursor, bucket);
    count_etypes<<<(N_EDGES + 255) / 256, 256, 0, stream>>>(etypes, cnt);
    calc_offsets<<<1, 64, 0, stream>>>(cnt, offs);
    scatter_edges<<<(N_EDGES + 255) / 256, 256, 0, stream>>>(etypes, offs, cursor, bucket);

    // h = feat @ W_loop + bias
    {
        dim3 g(KDIM / BN, N_NODES / BM);   // (8, 125)
        mfma_gemm<0><<<g, 256, 0, stream>>>(fb, wlT, bias, h, nullptr, nullptr, nullptr, nullptr);
    }
    // h[dst] += feat[src] @ W_rel[etype]
    {
        dim3 g(KDIM / BN, NTILE_E);        // (8, 1007)
        mfma_gemm<1><<<g, 256, 0, stream>>>(fb, wrT, nullptr, h, src, dst, bucket, offs);
    }
    // h -> bf16 (reuse feat_bf16 buffer)
    conv_bf16<<<(N_NODES * KDIM / 8 + 255) / 256, 256, 0, stream>>>(h, fb, N_NODES * KDIM / 8);
    // out = sigmoid(h @ go^T + |rad|)
    {
        dim3 g(NB_GOS / BN, N_NODES / BM); // (32, 125)
        mfma_gemm<2><<<g, 256, 0, stream>>>(fb, gob, go_rad, out, nullptr, nullptr, nullptr, nullptr);
    }
}

// Round 3
// 968.710 us; speedup vs baseline: 10.3065x; 2.1848x over previous
//
#include <hip/hip_runtime.h>
#include <math.h>

#define N_NODES 16000
#define N_EDGES 128000
#define KDIM 1024
#define N_RELS 7
#define NB_GOS 4096

#define BM 128
#define BN 128
#define BK 32
#define CAP2 (N_EDGES + N_RELS * BM)   // 128896 = 1007 * 128
#define NTILE_E (CAP2 / BM)            // 1007

typedef __attribute__((ext_vector_type(8))) short bf16x8;
typedef __attribute__((ext_vector_type(8))) unsigned short u16x8;
typedef __attribute__((ext_vector_type(4))) float f32x4;

__device__ __forceinline__ unsigned short f2bf(float f) {
    union { float f; unsigned int u; } v; v.f = f;
    unsigned int u = v.u + 0x7FFFu + ((v.u >> 16) & 1u);   // RNE
    return (unsigned short)(u >> 16);
}

__device__ __forceinline__ void gload16(const void* g, void* lds) {
    __builtin_amdgcn_global_load_lds(
        (const __attribute__((address_space(1))) unsigned int*)g,
        (__attribute__((address_space(3))) unsigned int*)lds, 16, 0, 0);
}

// ---------------- prep: fp32 -> bf16 (8 elements/thread) ----------------

__global__ __launch_bounds__(256) void conv_bf16(const float* __restrict__ in,
                                                 unsigned short* __restrict__ out, int n8) {
    int i = blockIdx.x * 256 + threadIdx.x;
    if (i >= n8) return;
    const float4* in4 = (const float4*)in;
    float4 x = in4[2 * i], y = in4[2 * i + 1];
    u16x8 o;
    o[0] = f2bf(x.x); o[1] = f2bf(x.y); o[2] = f2bf(x.z); o[3] = f2bf(x.w);
    o[4] = f2bf(y.x); o[5] = f2bf(y.y); o[6] = f2bf(y.z); o[7] = f2bf(y.w);
    *(u16x8*)&out[(size_t)i * 8] = o;
}

// transpose W ([K][N] fp32) -> [N][K] bf16, 8 matrices (7 W_rel + W_loop)
__global__ __launch_bounds__(256) void transpose_w(const float* __restrict__ Wrel,
                                                   const float* __restrict__ Wloop,
                                                   unsigned short* __restrict__ WrelT,
                                                   unsigned short* __restrict__ WloopT) {
    __shared__ float t[32][33];
    int z = blockIdx.z;
    const float* src = (z < N_RELS) ? Wrel + (size_t)z * KDIM * KDIM : Wloop;
    unsigned short* dst = (z < N_RELS) ? WrelT + (size_t)z * KDIM * KDIM : WloopT;
    int tx = threadIdx.x, ty = threadIdx.y;      // 32 x 8
    int x = blockIdx.x * 32 + tx;                // n
    int y0 = blockIdx.y * 32;                    // k base
    #pragma unroll
    for (int j = 0; j < 4; j++)
        t[ty + 8 * j][tx] = src[(size_t)(y0 + ty + 8 * j) * KDIM + x];
    __syncthreads();
    #pragma unroll
    for (int j = 0; j < 4; j++) {
        int n = blockIdx.x * 32 + ty + 8 * j;
        dst[(size_t)n * KDIM + y0 + tx] = f2bf(t[tx][ty + 8 * j]);
    }
}

// ---------------- bucket setup (de-contended) ----------------

__global__ void init_buckets(int* cnt, int* cursor, int* bucket) {
    int i = blockIdx.x * 256 + threadIdx.x;
    if (i < 8) { cnt[i] = 0; cursor[i] = 0; }
    if (i < CAP2) bucket[i] = -1;
}

// LDS histogram, then 7 global atomics per block (was: 128000 contended)
__global__ __launch_bounds__(256) void count_etypes(const int* __restrict__ et, int* cnt) {
    __shared__ int lc[N_RELS];
    if (threadIdx.x < N_RELS) lc[threadIdx.x] = 0;
    __syncthreads();
    int e = blockIdx.x * 256 + threadIdx.x;
    if (e < N_EDGES) atomicAdd(&lc[et[e]], 1);
    __syncthreads();
    if (threadIdx.x < N_RELS) atomicAdd(&cnt[threadIdx.x], lc[threadIdx.x]);
}

__global__ void calc_offsets(const int* __restrict__ cnt, int* offs) {
    if (blockIdx.x == 0 && threadIdx.x == 0) {
        int acc = 0;
        offs[0] = 0;
        for (int r = 0; r < N_RELS; r++) {
            acc += ((cnt[r] + BM - 1) / BM) * BM;
            offs[r + 1] = acc;
        }
    }
}

// block-local position via LDS atomic, one global cursor bump per (block, rel)
__global__ __launch_bounds__(256) void scatter_edges(const int* __restrict__ et,
                                                     const int* __restrict__ offs,
                                                     int* cursor, int* bucket) {
    __shared__ int lc[N_RELS];
    __shared__ int lbase[N_RELS];
    if (threadIdx.x < N_RELS) lc[threadIdx.x] = 0;
    __syncthreads();
    int e = blockIdx.x * 256 + threadIdx.x;
    int r = 0, my = 0;
    bool valid = (e < N_EDGES);
    if (valid) { r = et[e]; my = atomicAdd(&lc[r], 1); }
    __syncthreads();
    if (threadIdx.x < N_RELS)
        lbase[threadIdx.x] = atomicAdd(&cursor[threadIdx.x], lc[threadIdx.x]);
    __syncthreads();
    if (valid) bucket[offs[r] + lbase[r] + my] = e;
}

// ---------------- MFMA GEMM: 128x128 tile, BK=32, 4 waves (2x2) ----------------
// MODE 0: H[m] = feat @ W_loop^T(staged) + bias          (plain store, stride 1024)
// MODE 1: H[dst] += feat[src] @ W_rel[rel]               (atomicAdd, stride 1024)
// MODE 2: out[m] = sigmoid(h @ go^T + |rad|)             (store, stride 4096)
// Grid is (x, y) tiles; nwg % 8 == 0 for all modes -> bijective XCD swizzle,
// x-major chunks: each XCD owns a column slab (B-panel slice stays L2-resident).

template<int MODE>
__global__ __launch_bounds__(256) void mfma_gemm(
    const unsigned short* __restrict__ A,    // [*,1024] bf16
    const unsigned short* __restrict__ BT,   // [*,1024] bf16, rows = output cols
    const float* __restrict__ br,            // bias (MODE0) / rad (MODE2)
    float* __restrict__ out,
    const int* __restrict__ src,
    const int* __restrict__ dst,
    const int* __restrict__ bucket,
    const int* __restrict__ offs)
{
    __shared__ unsigned short As[BM * BK];
    __shared__ unsigned short Bs[BN * BK];
    __shared__ int s_src[BM];
    __shared__ int s_dst[BM];

    const int tid = threadIdx.x;
    const int l = tid & 63;
    const int w = tid >> 6;
    const int wr = w >> 1, wc = w & 1;

    // XCD-aware bijective swizzle (nwg % 8 == 0), x-major decomposition
    const int nwg = gridDim.x * gridDim.y;
    const int b = blockIdx.y * gridDim.x + blockIdx.x;
    const int cpx = nwg >> 3;
    const int swz = (b & 7) * cpx + (b >> 3);
    const int n0 = (swz / gridDim.y) * BN;
    const int m0 = (swz % gridDim.y) * BM;

    const unsigned short* Bb = BT;
    if (MODE == 1) {
        int rel = -1;
        #pragma unroll
        for (int q = 0; q < N_RELS; q++)
            if (m0 >= offs[q] && m0 < offs[q + 1]) rel = q;
        if (rel < 0) return;                       // uniform: tile past padded buckets
        Bb = BT + (size_t)rel * KDIM * KDIM;
        if (tid < BM) {
            int e = bucket[m0 + tid];
            s_src[tid] = (e >= 0) ? src[e] : -1;
            s_dst[tid] = (e >= 0) ? dst[e] : -1;
        }
        __syncthreads();
    }

    f32x4 acc[4][4] = {};

    // staging: 512 16B slots per operand; thread t owns slots t and t+256.
    const int s0 = tid, s1 = tid + 256;
    const int r0 = s0 >> 2, kc0 = (s0 & 3) * 8;
    const int r1 = s1 >> 2, kc1 = (s1 & 3) * 8;
    unsigned short* ldsA0 = As + (w * 64) * 8;           // wave-uniform bases
    unsigned short* ldsA1 = As + (w * 64 + 256) * 8;
    unsigned short* ldsB0 = Bs + (w * 64) * 8;
    unsigned short* ldsB1 = Bs + (w * 64 + 256) * 8;

    size_t arow0, arow1;
    if (MODE == 1) {
        int sr0 = s_src[r0]; arow0 = (sr0 < 0) ? 0 : (size_t)sr0;  // pad rows: clamp, dropped at epilogue
        int sr1 = s_src[r1]; arow1 = (sr1 < 0) ? 0 : (size_t)sr1;
    } else {
        arow0 = (size_t)(m0 + r0);
        arow1 = (size_t)(m0 + r1);
    }
    const size_t brow0 = (size_t)(n0 + r0), brow1 = (size_t)(n0 + r1);

    const int fa = (wr * 64 + (l & 15)) * BK + (l >> 4) * 8;
    const int fb = (wc * 64 + (l & 15)) * BK + (l >> 4) * 8;

    for (int k0 = 0; k0 < KDIM; k0 += BK) {
        gload16(A + arow0 * KDIM + k0 + kc0, ldsA0);
        gload16(A + arow1 * KDIM + k0 + kc1, ldsA1);
        gload16(Bb + brow0 * KDIM + k0 + kc0, ldsB0);
        gload16(Bb + brow1 * KDIM + k0 + kc1, ldsB1);
        __syncthreads();

        bf16x8 a[4], bfr[4];
        #pragma unroll
        for (int mi = 0; mi < 4; mi++)
            a[mi] = *(const bf16x8*)&As[fa + mi * 16 * BK];
        #pragma unroll
        for (int nj = 0; nj < 4; nj++)
            bfr[nj] = *(const bf16x8*)&Bs[fb + nj * 16 * BK];
        #pragma unroll
        for (int mi = 0; mi < 4; mi++)
            #pragma unroll
            for (int nj = 0; nj < 4; nj++)
                acc[mi][nj] = __builtin_amdgcn_mfma_f32_16x16x32_bf16(a[mi], bfr[nj], acc[mi][nj], 0, 0, 0);
        __syncthreads();
    }

    // epilogue — verified C/D layout: col = lane&15, row = (lane>>4)*4 + reg
    const int cl = l & 15, rh = (l >> 4) * 4;
    #pragma unroll
    for (int mi = 0; mi < 4; mi++) {
        #pragma unroll
        for (int r4 = 0; r4 < 4; r4++) {
            const int row = wr * 64 + mi * 16 + rh + r4;
            if (MODE == 1) {
                const int d = s_dst[row];
                if (d >= 0) {
                    #pragma unroll
                    for (int nj = 0; nj < 4; nj++) {
                        const int col = n0 + wc * 64 + nj * 16 + cl;
                        atomicAdd(&out[(size_t)d * KDIM + col], acc[mi][nj][r4]);
                    }
                }
            } else if (MODE == 0) {
                #pragma unroll
                for (int nj = 0; nj < 4; nj++) {
                    const int col = n0 + wc * 64 + nj * 16 + cl;
                    out[(size_t)(m0 + row) * KDIM + col] = acc[mi][nj][r4] + br[col];
                }
            } else {
                #pragma unroll
                for (int nj = 0; nj < 4; nj++) {
                    const int col = n0 + wc * 64 + nj * 16 + cl;
                    float x = acc[mi][nj][r4] + fabsf(br[col]);
                    out[(size_t)(m0 + row) * (size_t)NB_GOS + col] = 1.0f / (1.0f + expf(-x));
                }
            }
        }
    }
}

// ---------------- launch ----------------

extern "C" void kernel_launch(void* const* d_in, const int* in_sizes, int n_in,
                              void* d_out, int out_size, void* d_ws, size_t ws_size,
                              hipStream_t stream) {
    const float* feat   = (const float*)d_in[0];
    const int*   src    = (const int*)d_in[1];
    const int*   dst    = (const int*)d_in[2];
    const int*   etypes = (const int*)d_in[3];
    const float* W_rel  = (const float*)d_in[4];
    const float* W_loop = (const float*)d_in[5];
    const float* bias   = (const float*)d_in[6];
    const float* go_emb = (const float*)d_in[7];
    const float* go_rad = (const float*)d_in[8];
    float* out = (float*)d_out;

    // workspace layout (all offsets 256B-aligned); total ~124 MB
    char* p = (char*)d_ws;
    float* h            = (float*)p;            p += (size_t)N_NODES * KDIM * 4;     // 65,536,000
    unsigned short* fb  = (unsigned short*)p;   p += (size_t)N_NODES * KDIM * 2;     // 32,768,000 (reused as h_bf16)
    unsigned short* wrT = (unsigned short*)p;   p += (size_t)N_RELS * KDIM * KDIM * 2; // 14,680,064
    unsigned short* wlT = (unsigned short*)p;   p += (size_t)KDIM * KDIM * 2;        // 2,097,152
    unsigned short* gob = (unsigned short*)p;   p += (size_t)NB_GOS * KDIM * 2;      // 8,388,608
    int* cnt    = (int*)p;
    int* cursor = cnt + 8;
    int* offs   = cursor + 8;
    int* bucket = offs + 16;

    // prep: conversions + transposes + buckets
    conv_bf16<<<(N_NODES * KDIM / 8 + 255) / 256, 256, 0, stream>>>(feat, fb, N_NODES * KDIM / 8);
    conv_bf16<<<(NB_GOS * KDIM / 8 + 255) / 256, 256, 0, stream>>>(go_emb, gob, NB_GOS * KDIM / 8);
    {
        dim3 g(KDIM / 32, KDIM / 32, N_RELS + 1), b(32, 8);
        transpose_w<<<g, b, 0, stream>>>(W_rel, W_loop, wrT, wlT);
    }
    init_buckets<<<(CAP2 + 255) / 256, 256, 0, stream>>>(cnt, cursor, bucket);
    count_etypes<<<(N_EDGES + 255) / 256, 256, 0, stream>>>(etypes, cnt);
    calc_offsets<<<1, 64, 0, stream>>>(cnt, offs);
    scatter_edges<<<(N_EDGES + 255) / 256, 256, 0, stream>>>(etypes, offs, cursor, bucket);

    // h = feat @ W_loop + bias
    {
        dim3 g(KDIM / BN, N_NODES / BM);   // (8, 125) -> 1000 wgs
        mfma_gemm<0><<<g, 256, 0, stream>>>(fb, wlT, bias, h, nullptr, nullptr, nullptr, nullptr);
    }
    // h[dst] += feat[src] @ W_rel[etype]
    {
        dim3 g(KDIM / BN, NTILE_E);        // (8, 1007) -> 8056 wgs
        mfma_gemm<1><<<g, 256, 0, stream>>>(fb, wrT, nullptr, h, src, dst, bucket, offs);
    }
    // h -> bf16 (reuse feat_bf16 buffer)
    conv_bf16<<<(N_NODES * KDIM / 8 + 255) / 256, 256, 0, stream>>>(h, fb, N_NODES * KDIM / 8);
    // out = sigmoid(h @ go^T + |rad|)
    {
        dim3 g(NB_GOS / BN, N_NODES / BM); // (32, 125) -> 4000 wgs
        mfma_gemm<2><<<g, 256, 0, stream>>>(fb, gob, go_rad, out, nullptr, nullptr, nullptr, nullptr);
    }
}

// Round 4
// 941.033 us; speedup vs baseline: 10.6096x; 1.0294x over previous
//
#include <hip/hip_runtime.h>
#include <math.h>

#define N_NODES 16000
#define N_EDGES 128000
#define KDIM 1024
#define N_RELS 7
#define NB_GOS 4096
#define KCAT (KDIM * (N_RELS + 1))     // 8192: [feat | agg r0..r6]

#define BM 128
#define BN 128
#define BK 32
#define CAP2 (N_EDGES + N_RELS * BM)   // 128896 = 1007 * 128 (fallback path)
#define NTILE_E (CAP2 / BM)            // 1007

typedef __attribute__((ext_vector_type(8))) short bf16x8;
typedef __attribute__((ext_vector_type(8))) unsigned short u16x8;
typedef __attribute__((ext_vector_type(4))) float f32x4;

__device__ __forceinline__ unsigned short f2bf(float f) {
    union { float f; unsigned int u; } v; v.f = f;
    unsigned int u = v.u + 0x7FFFu + ((v.u >> 16) & 1u);   // RNE
    return (unsigned short)(u >> 16);
}

__device__ __forceinline__ void gload16(const void* g, void* lds) {
    __builtin_amdgcn_global_load_lds(
        (const __attribute__((address_space(1))) unsigned int*)g,
        (__attribute__((address_space(3))) unsigned int*)lds, 16, 0, 0);
}

// ---------------- generic fp32 -> bf16 (8 elements/thread) ----------------

__global__ __launch_bounds__(256) void conv_bf16(const float* __restrict__ in,
                                                 unsigned short* __restrict__ out, int n8) {
    int i = blockIdx.x * 256 + threadIdx.x;
    if (i >= n8) return;
    const float4* in4 = (const float4*)in;
    float4 x = in4[2 * i], y = in4[2 * i + 1];
    u16x8 o;
    o[0] = f2bf(x.x); o[1] = f2bf(x.y); o[2] = f2bf(x.z); o[3] = f2bf(x.w);
    o[4] = f2bf(y.x); o[5] = f2bf(y.y); o[6] = f2bf(y.z); o[7] = f2bf(y.w);
    *(u16x8*)&out[(size_t)i * 8] = o;
}

// feat fp32 -> bf16 into A_cat cols 0..1023 (row stride KCAT)
__global__ __launch_bounds__(256) void conv_cat(const float* __restrict__ in,
                                                unsigned short* __restrict__ Acat) {
    int i = blockIdx.x * 256 + threadIdx.x;    // 16000 * 128 items of 8
    if (i >= N_NODES * (KDIM / 8)) return;
    int n = i >> 7, c8 = (i & 127) * 8;
    const float4* in4 = (const float4*)(in + (size_t)n * KDIM + c8);
    float4 x = in4[0], y = in4[1];
    u16x8 o;
    o[0] = f2bf(x.x); o[1] = f2bf(x.y); o[2] = f2bf(x.z); o[3] = f2bf(x.w);
    o[4] = f2bf(y.x); o[5] = f2bf(y.y); o[6] = f2bf(y.z); o[7] = f2bf(y.w);
    *(u16x8*)&Acat[(size_t)n * KCAT + c8] = o;
}

// transpose W ([K][N] fp32) -> separate [N][K] bf16 (fallback path)
__global__ void transpose_w(const float* __restrict__ Wrel,
                            const float* __restrict__ Wloop,
                            unsigned short* __restrict__ WrelT,
                            unsigned short* __restrict__ WloopT) {
    __shared__ float t[32][33];
    int z = blockIdx.z;
    const float* src = (z < N_RELS) ? Wrel + (size_t)z * KDIM * KDIM : Wloop;
    unsigned short* dst = (z < N_RELS) ? WrelT + (size_t)z * KDIM * KDIM : WloopT;
    int tx = threadIdx.x, ty = threadIdx.y;      // 32 x 8
    int x = blockIdx.x * 32 + tx;
    int y0 = blockIdx.y * 32;
    #pragma unroll
    for (int j = 0; j < 4; j++)
        t[ty + 8 * j][tx] = src[(size_t)(y0 + ty + 8 * j) * KDIM + x];
    __syncthreads();
    #pragma unroll
    for (int j = 0; j < 4; j++) {
        int n = blockIdx.x * 32 + ty + 8 * j;
        dst[(size_t)n * KDIM + y0 + tx] = f2bf(t[tx][ty + 8 * j]);
    }
}

// transpose into concatenated BT_cat [1024][8192]: z=0 -> W_loop at k 0..1023,
// z=r+1 -> W_rel[r] at k z*1024..z*1024+1023
__global__ void transpose_cat(const float* __restrict__ Wrel,
                              const float* __restrict__ Wloop,
                              unsigned short* __restrict__ BT) {
    __shared__ float t[32][33];
    int z = blockIdx.z;
    const float* src = (z == 0) ? Wloop : Wrel + (size_t)(z - 1) * KDIM * KDIM;
    int tx = threadIdx.x, ty = threadIdx.y;      // 32 x 8
    int x = blockIdx.x * 32 + tx;                // output col o
    int y0 = blockIdx.y * 32;                    // k base
    #pragma unroll
    for (int j = 0; j < 4; j++)
        t[ty + 8 * j][tx] = src[(size_t)(y0 + ty + 8 * j) * KDIM + x];
    __syncthreads();
    #pragma unroll
    for (int j = 0; j < 4; j++) {
        int o = blockIdx.x * 32 + ty + 8 * j;
        BT[(size_t)o * KCAT + z * KDIM + y0 + tx] = f2bf(t[tx][ty + 8 * j]);
    }
}

// ---------------- dst-sort (fast path) ----------------

__global__ void zero_ints(int* p, int n) {
    int i = blockIdx.x * 256 + threadIdx.x;
    if (i < n) p[i] = 0;
}

__global__ void hist_dst(const int* __restrict__ dst, int* cnt) {
    int e = blockIdx.x * 256 + threadIdx.x;
    if (e < N_EDGES) atomicAdd(&cnt[dst[e]], 1);
}

__global__ __launch_bounds__(1024) void scan_offs(const int* __restrict__ cnt,
                                                  int* __restrict__ offs) {
    __shared__ int part[1024];
    int t = threadIdx.x;
    int base = t * 16;
    int local[16];
    int s = 0;
    if (base < N_NODES) {
        #pragma unroll
        for (int j = 0; j < 16; j++) { local[j] = cnt[base + j]; s += local[j]; }
    }
    part[t] = s;
    __syncthreads();
    for (int d = 1; d < 1024; d <<= 1) {
        int v = (t >= d) ? part[t - d] : 0;
        __syncthreads();
        part[t] += v;
        __syncthreads();
    }
    if (base < N_NODES) {
        int ex = (t == 0) ? 0 : part[t - 1];
        #pragma unroll
        for (int j = 0; j < 16; j++) { offs[base + j] = ex; ex += local[j]; }
        if (base + 16 == N_NODES) offs[N_NODES] = ex;
    }
}

__global__ void scatter_dst(const int* __restrict__ src, const int* __restrict__ dst,
                            const int* __restrict__ et, const int* __restrict__ offs,
                            int* cursor, int* __restrict__ se) {
    int e = blockIdx.x * 256 + threadIdx.x;
    if (e < N_EDGES) {
        int d = dst[e];
        int p = atomicAdd(&cursor[d], 1);
        se[offs[d] + p] = (src[e] << 3) | et[e];
    }
}

// per-node aggregation: block = dst node, thread owns 4 cols of all 7 rels
__global__ __launch_bounds__(256) void aggregate(const float* __restrict__ feat,
                                                 const int* __restrict__ offs,
                                                 const int* __restrict__ se,
                                                 unsigned short* __restrict__ Acat) {
    int n = blockIdx.x;
    int t = threadIdx.x;
    int e0 = offs[n], e1 = offs[n + 1];
    float4 a0 = {0,0,0,0}, a1 = a0, a2 = a0, a3 = a0, a4 = a0, a5 = a0, a6 = a0;
    const float4* f4 = (const float4*)feat;
    for (int i = e0; i < e1; i++) {
        int v = se[i];                     // wave-uniform
        int s = v >> 3, r = v & 7;
        float4 x = f4[(size_t)s * (KDIM / 4) + t];
        #define ADD4(a) { a.x += x.x; a.y += x.y; a.z += x.z; a.w += x.w; }
        switch (r) {                       // uniform branch (same edge blockwide)
            case 0: ADD4(a0) break; case 1: ADD4(a1) break;
            case 2: ADD4(a2) break; case 3: ADD4(a3) break;
            case 4: ADD4(a4) break; case 5: ADD4(a5) break;
            default: ADD4(a6) break;
        }
        #undef ADD4
    }
    unsigned short* row = Acat + (size_t)n * KCAT + KDIM;   // agg region
    #define ST4(rr, a) { ushort4 o; o.x = f2bf(a.x); o.y = f2bf(a.y); \
                         o.z = f2bf(a.z); o.w = f2bf(a.w); \
                         *(ushort4*)(row + rr * KDIM + t * 4) = o; }
    ST4(0, a0) ST4(1, a1) ST4(2, a2) ST4(3, a3) ST4(4, a4) ST4(5, a5) ST4(6, a6)
    #undef ST4
}

// ---------------- bucket setup (fallback path, de-contended) ----------------

__global__ void init_buckets(int* cnt, int* cursor, int* bucket) {
    int i = blockIdx.x * 256 + threadIdx.x;
    if (i < 8) { cnt[i] = 0; cursor[i] = 0; }
    if (i < CAP2) bucket[i] = -1;
}

__global__ __launch_bounds__(256) void count_etypes(const int* __restrict__ et, int* cnt) {
    __shared__ int lc[N_RELS];
    if (threadIdx.x < N_RELS) lc[threadIdx.x] = 0;
    __syncthreads();
    int e = blockIdx.x * 256 + threadIdx.x;
    if (e < N_EDGES) atomicAdd(&lc[et[e]], 1);
    __syncthreads();
    if (threadIdx.x < N_RELS) atomicAdd(&cnt[threadIdx.x], lc[threadIdx.x]);
}

__global__ void calc_offsets(const int* __restrict__ cnt, int* offs) {
    if (blockIdx.x == 0 && threadIdx.x == 0) {
        int acc = 0;
        offs[0] = 0;
        for (int r = 0; r < N_RELS; r++) {
            acc += ((cnt[r] + BM - 1) / BM) * BM;
            offs[r + 1] = acc;
        }
    }
}

__global__ __launch_bounds__(256) void scatter_edges(const int* __restrict__ et,
                                                     const int* __restrict__ offs,
                                                     int* cursor, int* bucket) {
    __shared__ int lc[N_RELS];
    __shared__ int lbase[N_RELS];
    if (threadIdx.x < N_RELS) lc[threadIdx.x] = 0;
    __syncthreads();
    int e = blockIdx.x * 256 + threadIdx.x;
    int r = 0, my = 0;
    bool valid = (e < N_EDGES);
    if (valid) { r = et[e]; my = atomicAdd(&lc[r], 1); }
    __syncthreads();
    if (threadIdx.x < N_RELS)
        lbase[threadIdx.x] = atomicAdd(&cursor[threadIdx.x], lc[threadIdx.x]);
    __syncthreads();
    if (valid) bucket[offs[r] + lbase[r] + my] = e;
}

// ---------------- MFMA GEMM: 128x128 tile, BK=32, 4 waves (2x2) ----------------
// MODE 0: out = A @ BT^T + bias (store, ldc=KDIM), runtime K (1024 or 8192)
// MODE 1: H[dst] += feat[src] @ W_rel[rel]  (atomicAdd epilogue; fallback path)
// MODE 2: out = sigmoid(A @ BT^T + |rad|)   (store, ldc=NB_GOS)
// Bijective XCD swizzle (nwg % 8 == 0), x-major chunks.

template<int MODE>
__global__ __launch_bounds__(256) void mfma_gemm(
    const unsigned short* __restrict__ A,
    const unsigned short* __restrict__ BT,
    const float* __restrict__ br,
    float* __restrict__ out,
    const int* __restrict__ src,
    const int* __restrict__ dst,
    const int* __restrict__ bucket,
    const int* __restrict__ offs,
    int kd)
{
    __shared__ unsigned short As[BM * BK];
    __shared__ unsigned short Bs[BN * BK];
    __shared__ int s_src[BM];
    __shared__ int s_dst[BM];

    const int tid = threadIdx.x;
    const int l = tid & 63;
    const int w = tid >> 6;
    const int wr = w >> 1, wc = w & 1;

    const int nwg = gridDim.x * gridDim.y;
    const int b = blockIdx.y * gridDim.x + blockIdx.x;
    const int cpx = nwg >> 3;
    const int swz = (b & 7) * cpx + (b >> 3);
    const int n0 = (swz / gridDim.y) * BN;
    const int m0 = (swz % gridDim.y) * BM;

    const unsigned short* Bb = BT;
    if (MODE == 1) {
        int rel = -1;
        #pragma unroll
        for (int q = 0; q < N_RELS; q++)
            if (m0 >= offs[q] && m0 < offs[q + 1]) rel = q;
        if (rel < 0) return;
        Bb = BT + (size_t)rel * KDIM * KDIM;
        if (tid < BM) {
            int e = bucket[m0 + tid];
            s_src[tid] = (e >= 0) ? src[e] : -1;
            s_dst[tid] = (e >= 0) ? dst[e] : -1;
        }
        __syncthreads();
    }

    f32x4 acc[4][4] = {};

    const int s0 = tid, s1 = tid + 256;
    const int r0 = s0 >> 2, kc0 = (s0 & 3) * 8;
    const int r1 = s1 >> 2, kc1 = (s1 & 3) * 8;
    unsigned short* ldsA0 = As + (w * 64) * 8;
    unsigned short* ldsA1 = As + (w * 64 + 256) * 8;
    unsigned short* ldsB0 = Bs + (w * 64) * 8;
    unsigned short* ldsB1 = Bs + (w * 64 + 256) * 8;

    size_t arow0, arow1;
    if (MODE == 1) {
        int sr0 = s_src[r0]; arow0 = (sr0 < 0) ? 0 : (size_t)sr0;
        int sr1 = s_src[r1]; arow1 = (sr1 < 0) ? 0 : (size_t)sr1;
    } else {
        arow0 = (size_t)(m0 + r0);
        arow1 = (size_t)(m0 + r1);
    }
    const size_t brow0 = (size_t)(n0 + r0), brow1 = (size_t)(n0 + r1);

    const int fa = (wr * 64 + (l & 15)) * BK + (l >> 4) * 8;
    const int fb = (wc * 64 + (l & 15)) * BK + (l >> 4) * 8;

    for (int k0 = 0; k0 < kd; k0 += BK) {
        gload16(A + arow0 * kd + k0 + kc0, ldsA0);
        gload16(A + arow1 * kd + k0 + kc1, ldsA1);
        gload16(Bb + brow0 * kd + k0 + kc0, ldsB0);
        gload16(Bb + brow1 * kd + k0 + kc1, ldsB1);
        __syncthreads();

        bf16x8 a[4], bfr[4];
        #pragma unroll
        for (int mi = 0; mi < 4; mi++)
            a[mi] = *(const bf16x8*)&As[fa + mi * 16 * BK];
        #pragma unroll
        for (int nj = 0; nj < 4; nj++)
            bfr[nj] = *(const bf16x8*)&Bs[fb + nj * 16 * BK];
        #pragma unroll
        for (int mi = 0; mi < 4; mi++)
            #pragma unroll
            for (int nj = 0; nj < 4; nj++)
                acc[mi][nj] = __builtin_amdgcn_mfma_f32_16x16x32_bf16(a[mi], bfr[nj], acc[mi][nj], 0, 0, 0);
        __syncthreads();
    }

    // epilogue — C/D layout: col = lane&15, row = (lane>>4)*4 + reg
    const int cl = l & 15, rh = (l >> 4) * 4;
    #pragma unroll
    for (int mi = 0; mi < 4; mi++) {
        #pragma unroll
        for (int r4 = 0; r4 < 4; r4++) {
            const int row = wr * 64 + mi * 16 + rh + r4;
            if (MODE == 1) {
                const int d = s_dst[row];
                if (d >= 0) {
                    #pragma unroll
                    for (int nj = 0; nj < 4; nj++) {
                        const int col = n0 + wc * 64 + nj * 16 + cl;
                        atomicAdd(&out[(size_t)d * KDIM + col], acc[mi][nj][r4]);
                    }
                }
            } else if (MODE == 0) {
                #pragma unroll
                for (int nj = 0; nj < 4; nj++) {
                    const int col = n0 + wc * 64 + nj * 16 + cl;
                    out[(size_t)(m0 + row) * KDIM + col] = acc[mi][nj][r4] + br[col];
                }
            } else {
                #pragma unroll
                for (int nj = 0; nj < 4; nj++) {
                    const int col = n0 + wc * 64 + nj * 16 + cl;
                    float x = acc[mi][nj][r4] + fabsf(br[col]);
                    out[(size_t)(m0 + row) * (size_t)NB_GOS + col] = 1.0f / (1.0f + expf(-x));
                }
            }
        }
    }
}

// ---------------- launch ----------------

extern "C" void kernel_launch(void* const* d_in, const int* in_sizes, int n_in,
                              void* d_out, int out_size, void* d_ws, size_t ws_size,
                              hipStream_t stream) {
    const float* feat   = (const float*)d_in[0];
    const int*   src    = (const int*)d_in[1];
    const int*   dst    = (const int*)d_in[2];
    const int*   etypes = (const int*)d_in[3];
    const float* W_rel  = (const float*)d_in[4];
    const float* W_loop = (const float*)d_in[5];
    const float* bias   = (const float*)d_in[6];
    const float* go_emb = (const float*)d_in[7];
    const float* go_rad = (const float*)d_in[8];
    float* out = (float*)d_out;

    // ---- fast-path workspace layout (~354 MB) ----
    const size_t ACAT_B = (size_t)N_NODES * KCAT * 2;   // 262,144,000
    const size_t H_B    = (size_t)N_NODES * KDIM * 4;   //  65,536,000
    const size_t BTC_B  = (size_t)KDIM * KCAT * 2;      //  16,777,216
    const size_t GOB_B  = (size_t)NB_GOS * KDIM * 2;    //   8,388,608
    const size_t CNT_B  = 16384 * 4;
    const size_t NEED   = ACAT_B + H_B + BTC_B + GOB_B + 3 * CNT_B + (size_t)N_EDGES * 4;

    if (ws_size >= NEED) {
        char* p = (char*)d_ws;
        unsigned short* Acat  = (unsigned short*)p;  p += ACAT_B;
        float*          h     = (float*)p;           p += H_B;
        unsigned short* BTcat = (unsigned short*)p;  p += BTC_B;
        unsigned short* gob   = (unsigned short*)p;  p += GOB_B;
        int* cnt    = (int*)p;                       p += CNT_B;
        int* cursor = (int*)p;                       p += CNT_B;
        int* offs   = (int*)p;                       p += CNT_B;
        int* se     = (int*)p;
        unsigned short* hb = (unsigned short*)d_ws;  // reuse Acat after big GEMM

        zero_ints<<<(2 * 16384 + 255) / 256, 256, 0, stream>>>(cnt, 2 * 16384); // cnt+cursor
        conv_cat<<<(N_NODES * (KDIM / 8) + 255) / 256, 256, 0, stream>>>(feat, Acat);
        conv_bf16<<<(NB_GOS * KDIM / 8 + 255) / 256, 256, 0, stream>>>(go_emb, gob, NB_GOS * KDIM / 8);
        {
            dim3 g(KDIM / 32, KDIM / 32, N_RELS + 1), b(32, 8);
            transpose_cat<<<g, b, 0, stream>>>(W_rel, W_loop, BTcat);
        }
        hist_dst<<<(N_EDGES + 255) / 256, 256, 0, stream>>>(dst, cnt);
        scan_offs<<<1, 1024, 0, stream>>>(cnt, offs);
        scatter_dst<<<(N_EDGES + 255) / 256, 256, 0, stream>>>(src, dst, etypes, offs, cursor, se);
        aggregate<<<N_NODES, 256, 0, stream>>>(feat, offs, se, Acat);

        // h = [feat | agg] @ [W_loop; W_rel]^T + bias   (K = 8192, no atomics)
        {
            dim3 g(KDIM / BN, N_NODES / BM);   // (8, 125) -> 1000 wgs
            mfma_gemm<0><<<g, 256, 0, stream>>>(Acat, BTcat, bias, h,
                                                nullptr, nullptr, nullptr, nullptr, KCAT);
        }
        conv_bf16<<<(N_NODES * KDIM / 8 + 255) / 256, 256, 0, stream>>>(h, hb, N_NODES * KDIM / 8);
        {
            dim3 g(NB_GOS / BN, N_NODES / BM); // (32, 125) -> 4000 wgs
            mfma_gemm<2><<<g, 256, 0, stream>>>(hb, gob, go_rad, out,
                                                nullptr, nullptr, nullptr, nullptr, KDIM);
        }
        return;
    }

    // ---- fallback: round-3 path (~124 MB ws) ----
    char* p = (char*)d_ws;
    float* h            = (float*)p;            p += (size_t)N_NODES * KDIM * 4;
    unsigned short* fb  = (unsigned short*)p;   p += (size_t)N_NODES * KDIM * 2;
    unsigned short* wrT = (unsigned short*)p;   p += (size_t)N_RELS * KDIM * KDIM * 2;
    unsigned short* wlT = (unsigned short*)p;   p += (size_t)KDIM * KDIM * 2;
    unsigned short* gob = (unsigned short*)p;   p += (size_t)NB_GOS * KDIM * 2;
    int* cnt    = (int*)p;
    int* cursor = cnt + 8;
    int* offs   = cursor + 8;
    int* bucket = offs + 16;

    conv_bf16<<<(N_NODES * KDIM / 8 + 255) / 256, 256, 0, stream>>>(feat, fb, N_NODES * KDIM / 8);
    conv_bf16<<<(NB_GOS * KDIM / 8 + 255) / 256, 256, 0, stream>>>(go_emb, gob, NB_GOS * KDIM / 8);
    {
        dim3 g(KDIM / 32, KDIM / 32, N_RELS + 1), b(32, 8);
        transpose_w<<<g, b, 0, stream>>>(W_rel, W_loop, wrT, wlT);
    }
    init_buckets<<<(CAP2 + 255) / 256, 256, 0, stream>>>(cnt, cursor, bucket);
    count_etypes<<<(N_EDGES + 255) / 256, 256, 0, stream>>>(etypes, cnt);
    calc_offsets<<<1, 64, 0, stream>>>(cnt, offs);
    scatter_edges<<<(N_EDGES + 255) / 256, 256, 0, stream>>>(etypes, offs, cursor, bucket);
    {
        dim3 g(KDIM / BN, N_NODES / BM);
        mfma_gemm<0><<<g, 256, 0, stream>>>(fb, wlT, bias, h, nullptr, nullptr, nullptr, nullptr, KDIM);
    }
    {
        dim3 g(KDIM / BN, NTILE_E);
        mfma_gemm<1><<<g, 256, 0, stream>>>(fb, wrT, nullptr, h, src, dst, bucket, offs, KDIM);
    }
    conv_bf16<<<(N_NODES * KDIM / 8 + 255) / 256, 256, 0, stream>>>(h, fb, N_NODES * KDIM / 8);
    {
        dim3 g(NB_GOS / BN, N_NODES / BM);
        mfma_gemm<2><<<g, 256, 0, stream>>>(fb, gob, go_rad, out, nullptr, nullptr, nullptr, nullptr, KDIM);
    }
}

// Round 5
// 681.018 us; speedup vs baseline: 14.6604x; 1.3818x over previous
//
#include <hip/hip_runtime.h>
#include <math.h>

#define N_NODES 16000
#define N_EDGES 128000
#define KDIM 1024
#define N_RELS 7
#define NB_GOS 4096
#define KCAT (KDIM * (N_RELS + 1))     // 8192: [feat | agg r0..r6]
#define MPAD 16128                     // 63 * 256

#define BM 128
#define BN 128
#define BK 32
#define CAP2 (N_EDGES + N_RELS * BM)   // fallback path
#define NTILE_E (CAP2 / BM)

typedef __attribute__((ext_vector_type(8))) short bf16x8;
typedef __attribute__((ext_vector_type(8))) unsigned short u16x8;
typedef __attribute__((ext_vector_type(4))) float f32x4;

__device__ __forceinline__ unsigned short f2bf(float f) {
    union { float f; unsigned int u; } v; v.f = f;
    unsigned int u = v.u + 0x7FFFu + ((v.u >> 16) & 1u);   // RNE
    return (unsigned short)(u >> 16);
}

__device__ __forceinline__ void gload16(const void* g, void* lds) {
    __builtin_amdgcn_global_load_lds(
        (const __attribute__((address_space(1))) unsigned int*)g,
        (__attribute__((address_space(3))) unsigned int*)lds, 16, 0, 0);
}

__device__ __forceinline__ void wg_barrier() {
    __builtin_amdgcn_sched_barrier(0);
    asm volatile("s_barrier" ::: "memory");
    __builtin_amdgcn_sched_barrier(0);
}

// ---------------- prep kernels ----------------

__global__ __launch_bounds__(256) void conv_bf16(const float* __restrict__ in,
                                                 unsigned short* __restrict__ out, int n8) {
    int i = blockIdx.x * 256 + threadIdx.x;
    if (i >= n8) return;
    const float4* in4 = (const float4*)in;
    float4 x = in4[2 * i], y = in4[2 * i + 1];
    u16x8 o;
    o[0] = f2bf(x.x); o[1] = f2bf(x.y); o[2] = f2bf(x.z); o[3] = f2bf(x.w);
    o[4] = f2bf(y.x); o[5] = f2bf(y.y); o[6] = f2bf(y.z); o[7] = f2bf(y.w);
    *(u16x8*)&out[(size_t)i * 8] = o;
}

__global__ __launch_bounds__(256) void conv_cat(const float* __restrict__ in,
                                                unsigned short* __restrict__ Acat) {
    int i = blockIdx.x * 256 + threadIdx.x;
    if (i >= N_NODES * (KDIM / 8)) return;
    int n = i >> 7, c8 = (i & 127) * 8;
    const float4* in4 = (const float4*)(in + (size_t)n * KDIM + c8);
    float4 x = in4[0], y = in4[1];
    u16x8 o;
    o[0] = f2bf(x.x); o[1] = f2bf(x.y); o[2] = f2bf(x.z); o[3] = f2bf(x.w);
    o[4] = f2bf(y.x); o[5] = f2bf(y.y); o[6] = f2bf(y.z); o[7] = f2bf(y.w);
    *(u16x8*)&Acat[(size_t)n * KCAT + c8] = o;
}

__global__ void transpose_w(const float* __restrict__ Wrel,
                            const float* __restrict__ Wloop,
                            unsigned short* __restrict__ WrelT,
                            unsigned short* __restrict__ WloopT) {
    __shared__ float t[32][33];
    int z = blockIdx.z;
    const float* src = (z < N_RELS) ? Wrel + (size_t)z * KDIM * KDIM : Wloop;
    unsigned short* dst = (z < N_RELS) ? WrelT + (size_t)z * KDIM * KDIM : WloopT;
    int tx = threadIdx.x, ty = threadIdx.y;
    int x = blockIdx.x * 32 + tx;
    int y0 = blockIdx.y * 32;
    #pragma unroll
    for (int j = 0; j < 4; j++)
        t[ty + 8 * j][tx] = src[(size_t)(y0 + ty + 8 * j) * KDIM + x];
    __syncthreads();
    #pragma unroll
    for (int j = 0; j < 4; j++) {
        int n = blockIdx.x * 32 + ty + 8 * j;
        dst[(size_t)n * KDIM + y0 + tx] = f2bf(t[tx][ty + 8 * j]);
    }
}

__global__ void transpose_cat(const float* __restrict__ Wrel,
                              const float* __restrict__ Wloop,
                              unsigned short* __restrict__ BT) {
    __shared__ float t[32][33];
    int z = blockIdx.z;
    const float* src = (z == 0) ? Wloop : Wrel + (size_t)(z - 1) * KDIM * KDIM;
    int tx = threadIdx.x, ty = threadIdx.y;
    int x = blockIdx.x * 32 + tx;
    int y0 = blockIdx.y * 32;
    #pragma unroll
    for (int j = 0; j < 4; j++)
        t[ty + 8 * j][tx] = src[(size_t)(y0 + ty + 8 * j) * KDIM + x];
    __syncthreads();
    #pragma unroll
    for (int j = 0; j < 4; j++) {
        int o = blockIdx.x * 32 + ty + 8 * j;
        BT[(size_t)o * KCAT + z * KDIM + y0 + tx] = f2bf(t[tx][ty + 8 * j]);
    }
}

// ---------------- dst-sort + aggregation (fast path) ----------------

__global__ void zero_ints(int* p, int n) {
    int i = blockIdx.x * 256 + threadIdx.x;
    if (i < n) p[i] = 0;
}

__global__ void hist_dst(const int* __restrict__ dst, int* cnt) {
    int e = blockIdx.x * 256 + threadIdx.x;
    if (e < N_EDGES) atomicAdd(&cnt[dst[e]], 1);
}

__global__ __launch_bounds__(1024) void scan_offs(const int* __restrict__ cnt,
                                                  int* __restrict__ offs) {
    __shared__ int part[1024];
    int t = threadIdx.x;
    int base = t * 16;
    int local[16];
    int s = 0;
    if (base < N_NODES) {
        #pragma unroll
        for (int j = 0; j < 16; j++) { local[j] = cnt[base + j]; s += local[j]; }
    }
    part[t] = s;
    __syncthreads();
    for (int d = 1; d < 1024; d <<= 1) {
        int v = (t >= d) ? part[t - d] : 0;
        __syncthreads();
        part[t] += v;
        __syncthreads();
    }
    if (base < N_NODES) {
        int ex = (t == 0) ? 0 : part[t - 1];
        #pragma unroll
        for (int j = 0; j < 16; j++) { offs[base + j] = ex; ex += local[j]; }
        if (base + 16 == N_NODES) offs[N_NODES] = ex;
    }
}

__global__ void scatter_dst(const int* __restrict__ src, const int* __restrict__ dst,
                            const int* __restrict__ et, const int* __restrict__ offs,
                            int* cursor, int* __restrict__ se) {
    int e = blockIdx.x * 256 + threadIdx.x;
    if (e < N_EDGES) {
        int d = dst[e];
        int p = atomicAdd(&cursor[d], 1);
        se[offs[d] + p] = (src[e] << 3) | et[e];
    }
}

__global__ __launch_bounds__(256) void aggregate(const float* __restrict__ feat,
                                                 const int* __restrict__ offs,
                                                 const int* __restrict__ se,
                                                 unsigned short* __restrict__ Acat) {
    int n = blockIdx.x;
    int t = threadIdx.x;
    int e0 = offs[n], e1 = offs[n + 1];
    float4 a0 = {0,0,0,0}, a1 = a0, a2 = a0, a3 = a0, a4 = a0, a5 = a0, a6 = a0;
    const float4* f4 = (const float4*)feat;
    for (int i = e0; i < e1; i++) {
        int v = se[i];
        int s = v >> 3, r = v & 7;
        float4 x = f4[(size_t)s * (KDIM / 4) + t];
        #define ADD4(a) { a.x += x.x; a.y += x.y; a.z += x.z; a.w += x.w; }
        switch (r) {
            case 0: ADD4(a0) break; case 1: ADD4(a1) break;
            case 2: ADD4(a2) break; case 3: ADD4(a3) break;
            case 4: ADD4(a4) break; case 5: ADD4(a5) break;
            default: ADD4(a6) break;
        }
        #undef ADD4
    }
    unsigned short* row = Acat + (size_t)n * KCAT + KDIM;
    #define ST4(rr, a) { ushort4 o; o.x = f2bf(a.x); o.y = f2bf(a.y); \
                         o.z = f2bf(a.z); o.w = f2bf(a.w); \
                         *(ushort4*)(row + rr * KDIM + t * 4) = o; }
    ST4(0, a0) ST4(1, a1) ST4(2, a2) ST4(3, a3) ST4(4, a4) ST4(5, a5) ST4(6, a6)
    #undef ST4
}

// ======== 256x256 8-phase GEMM (T2+T3+T4+T5), BK=64, 8 waves (2Mx4N) ========
// MODE 0: out = A @ BT^T + bias   (fp32 store, ldc = KDIM)
// MODE 2: out = sigmoid(A @ BT^T + |rad|), rows >= 16000 masked (ldc = NB_GOS)
// LDS: linear [256][64] bf16 per operand, chunk-XOR swizzle (chunk ^= row&7)
// applied via inverse-swizzled GLOBAL source (global_load_lds writes linearly).
// Half-tile rotation per K-tile T (phases q0..q3 compute quads 0..3):
//   q0 stages (T+1).Ahi   [slot's last read: T-1.q3]
//   q1 stages (T+2).Blo   [last read T.q0]
//   q2 stages (T+2).Alo   [last read T.q1: quads 0,1 = rows {0-63,128-191}]
//   q3 stages (T+2).Bhi   [last read T.q0]; then s_waitcnt vmcnt(6)
// vmcnt(6) = 2 loads x 3 half-tiles in flight; never 0 in steady state.

template<int MODE>
__global__ __launch_bounds__(512, 2) void gemm256(
    const unsigned short* __restrict__ A,    // [Mpad][kd] bf16
    const unsigned short* __restrict__ BT,   // [N][kd] bf16 (rows = out cols)
    const float* __restrict__ br,            // bias / rad
    float* __restrict__ out, int kd)
{
    __shared__ unsigned short As[2][256 * 64];
    __shared__ unsigned short Bs[2][256 * 64];

    const int tid = threadIdx.x;
    const int l = tid & 63, w = tid >> 6;
    const int wm = w >> 2, wn = w & 3;

    // bijective XCD swizzle, m-major linear (consecutive wgids share A slab)
    const int nwg = gridDim.x * gridDim.y;
    const int b = blockIdx.y * gridDim.x + blockIdx.x;
    const int q8 = nwg >> 3, r8 = nwg & 7;
    const int xcd = b & 7, idx = b >> 3;
    const int wg = (xcd < r8 ? xcd * (q8 + 1) : r8 * (q8 + 1) + (xcd - r8) * q8) + idx;
    const int m0 = (wg / gridDim.x) * 256;
    const int n0 = (wg % gridDim.x) * 256;

    const int NT = kd >> 6;

    // staging geometry: thread -> (row-in-stripe, pre-swizzled chunk)
    const int rr = tid >> 3;                    // 0..63
    const int cc = (tid & 7) ^ (rr & 7);        // inverse-swizzled global chunk

    auto stageA = [&](int dbuf, int kt, int half) {
        #pragma unroll
        for (int j = 0; j < 2; j++) {
            unsigned short* lp = &As[dbuf][(size_t)(w * 8 + j * 128 + half * 64) * 64];
            const unsigned short* gp = A + (size_t)(m0 + rr + j * 128 + half * 64) * kd
                                         + kt * 64 + cc * 8;
            gload16(gp, lp);
        }
    };
    auto stageB = [&](int dbuf, int kt, int half) {
        #pragma unroll
        for (int j = 0; j < 2; j++) {
            unsigned short* lp = &Bs[dbuf][(size_t)(w * 8 + j * 64 + half * 128) * 64];
            const unsigned short* gp = BT + (size_t)(n0 + rr + j * 64 + half * 128) * kd
                                          + kt * 64 + cc * 8;
            gload16(gp, lp);
        }
    };

    // prologue: tile0 fully + tile1 {Blo, Alo, Bhi}; Ahi(t1) staged at t0.q0
    stageB(0, 0, 0); stageA(0, 0, 0); stageB(0, 0, 1); stageA(0, 0, 1);
    if (NT > 1) {
        stageB(1, 1, 0); stageA(1, 1, 0); stageB(1, 1, 1);
        asm volatile("s_waitcnt vmcnt(6)" ::: "memory");
    } else {
        asm volatile("s_waitcnt vmcnt(0)" ::: "memory");
    }
    wg_barrier();

    f32x4 acc[8][4] = {};

    for (int t = 0; t < NT; t++) {
        const int buf = t & 1;
        bf16x8 bfr[4][2];
        #pragma unroll
        for (int q = 0; q < 4; q++) {
            bf16x8 afr[2][2];
            if (q == 0) {
                #pragma unroll
                for (int nj = 0; nj < 4; nj++)
                    #pragma unroll
                    for (int ks = 0; ks < 2; ks++) {
                        int row = wn * 64 + nj * 16 + (l & 15);
                        int ch = (ks * 4 + (l >> 4)) ^ (l & 7);
                        bfr[nj][ks] = *(const bf16x8*)&Bs[buf][row * 64 + ch * 8];
                    }
            }
            #pragma unroll
            for (int i = 0; i < 2; i++)
                #pragma unroll
                for (int ks = 0; ks < 2; ks++) {
                    int row = wm * 128 + (2 * q + i) * 16 + (l & 15);
                    int ch = (ks * 4 + (l >> 4)) ^ (l & 7);
                    afr[i][ks] = *(const bf16x8*)&As[buf][row * 64 + ch * 8];
                }
            // one half-tile prefetch per phase
            if (q == 0)      { if (t + 1 < NT) stageA(buf ^ 1, t + 1, 1); }
            else if (q == 1) { if (t + 2 < NT) stageB(buf, t + 2, 0); }
            else if (q == 2) { if (t + 2 < NT) stageA(buf, t + 2, 0); }
            else             { if (t + 2 < NT) stageB(buf, t + 2, 1); }
            wg_barrier();
            __builtin_amdgcn_s_setprio(1);
            #pragma unroll
            for (int i = 0; i < 2; i++)
                #pragma unroll
                for (int nj = 0; nj < 4; nj++)
                    #pragma unroll
                    for (int ks = 0; ks < 2; ks++)
                        acc[2 * q + i][nj] = __builtin_amdgcn_mfma_f32_16x16x32_bf16(
                            afr[i][ks], bfr[nj][ks], acc[2 * q + i][nj], 0, 0, 0);
            __builtin_amdgcn_s_setprio(0);
            if (q == 3) {
                if (t + 2 < NT) asm volatile("s_waitcnt vmcnt(6)" ::: "memory");
                else            asm volatile("s_waitcnt vmcnt(0)" ::: "memory");
            }
            wg_barrier();
        }
    }

    // epilogue — C/D layout: col = lane&15, row = (lane>>4)*4 + reg
    const int cl = l & 15, rh = (l >> 4) * 4;
    float brv[4];
    #pragma unroll
    for (int nj = 0; nj < 4; nj++) brv[nj] = br[n0 + wn * 64 + nj * 16 + cl];
    #pragma unroll
    for (int mi = 0; mi < 8; mi++) {
        #pragma unroll
        for (int r4 = 0; r4 < 4; r4++) {
            const int row = m0 + wm * 128 + mi * 16 + rh + r4;
            if (MODE == 2 && row >= N_NODES) continue;
            #pragma unroll
            for (int nj = 0; nj < 4; nj++) {
                const int col = n0 + wn * 64 + nj * 16 + cl;
                float x = acc[mi][nj][r4];
                if (MODE == 0) {
                    out[(size_t)row * KDIM + col] = x + brv[nj];
                } else {
                    x += fabsf(brv[nj]);
                    out[(size_t)row * (size_t)NB_GOS + col] = 1.0f / (1.0f + __expf(-x));
                }
            }
        }
    }
}

// ---------------- fallback 128x128 GEMM (round-3/4, unchanged) ----------------

__global__ void init_buckets(int* cnt, int* cursor, int* bucket) {
    int i = blockIdx.x * 256 + threadIdx.x;
    if (i < 8) { cnt[i] = 0; cursor[i] = 0; }
    if (i < CAP2) bucket[i] = -1;
}

__global__ __launch_bounds__(256) void count_etypes(const int* __restrict__ et, int* cnt) {
    __shared__ int lc[N_RELS];
    if (threadIdx.x < N_RELS) lc[threadIdx.x] = 0;
    __syncthreads();
    int e = blockIdx.x * 256 + threadIdx.x;
    if (e < N_EDGES) atomicAdd(&lc[et[e]], 1);
    __syncthreads();
    if (threadIdx.x < N_RELS) atomicAdd(&cnt[threadIdx.x], lc[threadIdx.x]);
}

__global__ void calc_offsets(const int* __restrict__ cnt, int* offs) {
    if (blockIdx.x == 0 && threadIdx.x == 0) {
        int acc = 0;
        offs[0] = 0;
        for (int r = 0; r < N_RELS; r++) {
            acc += ((cnt[r] + BM - 1) / BM) * BM;
            offs[r + 1] = acc;
        }
    }
}

__global__ __launch_bounds__(256) void scatter_edges(const int* __restrict__ et,
                                                     const int* __restrict__ offs,
                                                     int* cursor, int* bucket) {
    __shared__ int lc[N_RELS];
    __shared__ int lbase[N_RELS];
    if (threadIdx.x < N_RELS) lc[threadIdx.x] = 0;
    __syncthreads();
    int e = blockIdx.x * 256 + threadIdx.x;
    int r = 0, my = 0;
    bool valid = (e < N_EDGES);
    if (valid) { r = et[e]; my = atomicAdd(&lc[r], 1); }
    __syncthreads();
    if (threadIdx.x < N_RELS)
        lbase[threadIdx.x] = atomicAdd(&cursor[threadIdx.x], lc[threadIdx.x]);
    __syncthreads();
    if (valid) bucket[offs[r] + lbase[r] + my] = e;
}

template<int MODE>
__global__ __launch_bounds__(256) void mfma_gemm(
    const unsigned short* __restrict__ A,
    const unsigned short* __restrict__ BT,
    const float* __restrict__ br,
    float* __restrict__ out,
    const int* __restrict__ src,
    const int* __restrict__ dst,
    const int* __restrict__ bucket,
    const int* __restrict__ offs,
    int kd)
{
    __shared__ unsigned short As[BM * BK];
    __shared__ unsigned short Bs[BN * BK];
    __shared__ int s_src[BM];
    __shared__ int s_dst[BM];

    const int tid = threadIdx.x;
    const int l = tid & 63;
    const int w = tid >> 6;
    const int wr = w >> 1, wc = w & 1;

    const int nwg = gridDim.x * gridDim.y;
    const int b = blockIdx.y * gridDim.x + blockIdx.x;
    const int cpx = nwg >> 3;
    const int swz = (b & 7) * cpx + (b >> 3);
    const int n0 = (swz / gridDim.y) * BN;
    const int m0 = (swz % gridDim.y) * BM;

    const unsigned short* Bb = BT;
    if (MODE == 1) {
        int rel = -1;
        #pragma unroll
        for (int q = 0; q < N_RELS; q++)
            if (m0 >= offs[q] && m0 < offs[q + 1]) rel = q;
        if (rel < 0) return;
        Bb = BT + (size_t)rel * KDIM * KDIM;
        if (tid < BM) {
            int e = bucket[m0 + tid];
            s_src[tid] = (e >= 0) ? src[e] : -1;
            s_dst[tid] = (e >= 0) ? dst[e] : -1;
        }
        __syncthreads();
    }

    f32x4 acc[4][4] = {};

    const int s0 = tid, s1 = tid + 256;
    const int r0 = s0 >> 2, kc0 = (s0 & 3) * 8;
    const int r1 = s1 >> 2, kc1 = (s1 & 3) * 8;
    unsigned short* ldsA0 = As + (w * 64) * 8;
    unsigned short* ldsA1 = As + (w * 64 + 256) * 8;
    unsigned short* ldsB0 = Bs + (w * 64) * 8;
    unsigned short* ldsB1 = Bs + (w * 64 + 256) * 8;

    size_t arow0, arow1;
    if (MODE == 1) {
        int sr0 = s_src[r0]; arow0 = (sr0 < 0) ? 0 : (size_t)sr0;
        int sr1 = s_src[r1]; arow1 = (sr1 < 0) ? 0 : (size_t)sr1;
    } else {
        arow0 = (size_t)(m0 + r0);
        arow1 = (size_t)(m0 + r1);
    }
    const size_t brow0 = (size_t)(n0 + r0), brow1 = (size_t)(n0 + r1);

    const int fa = (wr * 64 + (l & 15)) * BK + (l >> 4) * 8;
    const int fb = (wc * 64 + (l & 15)) * BK + (l >> 4) * 8;

    for (int k0 = 0; k0 < kd; k0 += BK) {
        gload16(A + arow0 * kd + k0 + kc0, ldsA0);
        gload16(A + arow1 * kd + k0 + kc1, ldsA1);
        gload16(Bb + brow0 * kd + k0 + kc0, ldsB0);
        gload16(Bb + brow1 * kd + k0 + kc1, ldsB1);
        __syncthreads();

        bf16x8 a[4], bfr[4];
        #pragma unroll
        for (int mi = 0; mi < 4; mi++)
            a[mi] = *(const bf16x8*)&As[fa + mi * 16 * BK];
        #pragma unroll
        for (int nj = 0; nj < 4; nj++)
            bfr[nj] = *(const bf16x8*)&Bs[fb + nj * 16 * BK];
        #pragma unroll
        for (int mi = 0; mi < 4; mi++)
            #pragma unroll
            for (int nj = 0; nj < 4; nj++)
                acc[mi][nj] = __builtin_amdgcn_mfma_f32_16x16x32_bf16(a[mi], bfr[nj], acc[mi][nj], 0, 0, 0);
        __syncthreads();
    }

    const int cl = l & 15, rh = (l >> 4) * 4;
    #pragma unroll
    for (int mi = 0; mi < 4; mi++) {
        #pragma unroll
        for (int r4 = 0; r4 < 4; r4++) {
            const int row = wr * 64 + mi * 16 + rh + r4;
            if (MODE == 1) {
                const int d = s_dst[row];
                if (d >= 0) {
                    #pragma unroll
                    for (int nj = 0; nj < 4; nj++) {
                        const int col = n0 + wc * 64 + nj * 16 + cl;
                        atomicAdd(&out[(size_t)d * KDIM + col], acc[mi][nj][r4]);
                    }
                }
            } else if (MODE == 0) {
                #pragma unroll
                for (int nj = 0; nj < 4; nj++) {
                    const int col = n0 + wc * 64 + nj * 16 + cl;
                    out[(size_t)(m0 + row) * KDIM + col] = acc[mi][nj][r4] + br[col];
                }
            } else {
                #pragma unroll
                for (int nj = 0; nj < 4; nj++) {
                    const int col = n0 + wc * 64 + nj * 16 + cl;
                    float x = acc[mi][nj][r4] + fabsf(br[col]);
                    out[(size_t)(m0 + row) * (size_t)NB_GOS + col] = 1.0f / (1.0f + expf(-x));
                }
            }
        }
    }
}

// ---------------- launch ----------------

extern "C" void kernel_launch(void* const* d_in, const int* in_sizes, int n_in,
                              void* d_out, int out_size, void* d_ws, size_t ws_size,
                              hipStream_t stream) {
    const float* feat   = (const float*)d_in[0];
    const int*   src    = (const int*)d_in[1];
    const int*   dst    = (const int*)d_in[2];
    const int*   etypes = (const int*)d_in[3];
    const float* W_rel  = (const float*)d_in[4];
    const float* W_loop = (const float*)d_in[5];
    const float* bias   = (const float*)d_in[6];
    const float* go_emb = (const float*)d_in[7];
    const float* go_rad = (const float*)d_in[8];
    float* out = (float*)d_out;

    // ---- fast-path workspace layout (~358 MB) ----
    const size_t ACAT_B = (size_t)MPAD * KCAT * 2;      // 264,241,152
    const size_t H_B    = (size_t)MPAD * KDIM * 4;      //  66,060,288
    const size_t BTC_B  = (size_t)KDIM * KCAT * 2;      //  16,777,216
    const size_t GOB_B  = (size_t)NB_GOS * KDIM * 2;    //   8,388,608
    const size_t CNT_B  = 16384 * 4;
    const size_t NEED   = ACAT_B + H_B + BTC_B + GOB_B + 3 * CNT_B + (size_t)N_EDGES * 4;

    if (ws_size >= NEED) {
        char* p = (char*)d_ws;
        unsigned short* Acat  = (unsigned short*)p;  p += ACAT_B;
        float*          h     = (float*)p;           p += H_B;
        unsigned short* BTcat = (unsigned short*)p;  p += BTC_B;
        unsigned short* gob   = (unsigned short*)p;  p += GOB_B;
        int* cnt    = (int*)p;                       p += CNT_B;
        int* cursor = (int*)p;                       p += CNT_B;
        int* offs   = (int*)p;                       p += CNT_B;
        int* se     = (int*)p;
        unsigned short* hb = (unsigned short*)d_ws;  // reuse Acat region after big GEMM

        zero_ints<<<(2 * 16384 + 255) / 256, 256, 0, stream>>>(cnt, 2 * 16384);
        conv_cat<<<(N_NODES * (KDIM / 8) + 255) / 256, 256, 0, stream>>>(feat, Acat);
        conv_bf16<<<(NB_GOS * KDIM / 8 + 255) / 256, 256, 0, stream>>>(go_emb, gob, NB_GOS * KDIM / 8);
        {
            dim3 g(KDIM / 32, KDIM / 32, N_RELS + 1), bb(32, 8);
            transpose_cat<<<g, bb, 0, stream>>>(W_rel, W_loop, BTcat);
        }
        hist_dst<<<(N_EDGES + 255) / 256, 256, 0, stream>>>(dst, cnt);
        scan_offs<<<1, 1024, 0, stream>>>(cnt, offs);
        scatter_dst<<<(N_EDGES + 255) / 256, 256, 0, stream>>>(src, dst, etypes, offs, cursor, se);
        aggregate<<<N_NODES, 256, 0, stream>>>(feat, offs, se, Acat);

        // h = [feat | agg] @ [W_loop; W_rel]^T + bias   (K = 8192, 8-phase 256^2)
        {
            dim3 g(KDIM / 256, MPAD / 256);    // (4, 63) -> 252 wgs
            gemm256<0><<<g, 512, 0, stream>>>(Acat, BTcat, bias, h, KCAT);
        }
        conv_bf16<<<(N_NODES * KDIM / 8 + 255) / 256, 256, 0, stream>>>(h, hb, N_NODES * KDIM / 8);
        // out = sigmoid(h @ go^T + |rad|)   (K = 1024, 8-phase 256^2)
        {
            dim3 g(NB_GOS / 256, MPAD / 256);  // (16, 63) -> 1008 wgs
            gemm256<2><<<g, 512, 0, stream>>>(hb, gob, go_rad, out, KDIM);
        }
        return;
    }

    // ---- fallback: round-3/4 path (~124 MB ws) ----
    char* p = (char*)d_ws;
    float* h            = (float*)p;            p += (size_t)N_NODES * KDIM * 4;
    unsigned short* fb  = (unsigned short*)p;   p += (size_t)N_NODES * KDIM * 2;
    unsigned short* wrT = (unsigned short*)p;   p += (size_t)N_RELS * KDIM * KDIM * 2;
    unsigned short* wlT = (unsigned short*)p;   p += (size_t)KDIM * KDIM * 2;
    unsigned short* gob = (unsigned short*)p;   p += (size_t)NB_GOS * KDIM * 2;
    int* cnt    = (int*)p;
    int* cursor = cnt + 8;
    int* offs   = cursor + 8;
    int* bucket = offs + 16;

    conv_bf16<<<(N_NODES * KDIM / 8 + 255) / 256, 256, 0, stream>>>(feat, fb, N_NODES * KDIM / 8);
    conv_bf16<<<(NB_GOS * KDIM / 8 + 255) / 256, 256, 0, stream>>>(go_emb, gob, NB_GOS * KDIM / 8);
    {
        dim3 g(KDIM / 32, KDIM / 32, N_RELS + 1), bb(32, 8);
        transpose_w<<<g, bb, 0, stream>>>(W_rel, W_loop, wrT, wlT);
    }
    init_buckets<<<(CAP2 + 255) / 256, 256, 0, stream>>>(cnt, cursor, bucket);
    count_etypes<<<(N_EDGES + 255) / 256, 256, 0, stream>>>(etypes, cnt);
    calc_offsets<<<1, 64, 0, stream>>>(cnt, offs);
    scatter_edges<<<(N_EDGES + 255) / 256, 256, 0, stream>>>(etypes, offs, cursor, bucket);
    {
        dim3 g(KDIM / BN, N_NODES / BM);
        mfma_gemm<0><<<g, 256, 0, stream>>>(fb, wlT, bias, h, nullptr, nullptr, nullptr, nullptr, KDIM);
    }
    {
        dim3 g(KDIM / BN, NTILE_E);
        mfma_gemm<1><<<g, 256, 0, stream>>>(fb, wrT, nullptr, h, src, dst, bucket, offs, KDIM);
    }
    conv_bf16<<<(N_NODES * KDIM / 8 + 255) / 256, 256, 0, stream>>>(h, fb, N_NODES * KDIM / 8);
    {
        dim3 g(NB_GOS / BN, N_NODES / BM);
        mfma_gemm<2><<<g, 256, 0, stream>>>(fb, gob, go_rad, out, nullptr, nullptr, nullptr, nullptr, KDIM);
    }
}